// Round 6
// baseline (141.125 us; speedup 1.0000x reference)
//
#include <hip/hip_runtime.h>
#include <math.h>

// Problem constants
#define BB    16      // batch
#define CC    64      // channels
#define HW    441     // h*w
#define QP    448     // padded to 28 tiles of 16
#define NCLS  10
#define MM    2205
#define MP    2208    // padded to 138 tiles of 16 = 69 pairs
#define NSPLIT 8      // m-splits: 7 splits of 9 pairs + 1 split of 6 pairs
#define CHUNK_T 6     // tiles per LDS chunk (3 pairs)
#define CHUNK_BYTES (CHUNK_T * 16 * CC * 2)   // 12288

typedef _Float16 half8 __attribute__((ext_vector_type(8)));
typedef float   float4_ __attribute__((ext_vector_type(4)));

// s_waitcnt with vmcnt(n), lgkmcnt/expcnt = no-wait (gfx9 encoding)
#define WAIT_VMCNT(n) __builtin_amdgcn_s_waitcnt(0x0F70 | (n))

// async global->LDS 16B per lane; lds dest = uniform base + lane*16
#define GLDS16(g, l) __builtin_amdgcn_global_load_lds(                         \
    (const __attribute__((address_space(1))) unsigned int*)(const void*)(g),   \
    (__attribute__((address_space(3))) unsigned int*)(void*)(l), 16, 0, 0)

// sorted top-2 insert (a0>=a1): 2 ops
__device__ __forceinline__ void ins2(float d, float& a0, float& a1) {
    float n0 = fmaxf(d, a0);
    float n1 = __builtin_amdgcn_fmed3f(d, a0, a1);
    a0 = n0; a1 = n1;
}

// merge sorted triple (b0>=b1>=b2) into sorted triple (a0>=a1>=a2): 6 ops
__device__ __forceinline__ void mrg3(float b0, float b1, float b2,
                                     float& a0, float& a1, float& a2) {
    float c0 = fmaxf(a0, b0);
    float c1 = fmaxf(fmaxf(fminf(a0, b0), a1), b1);
    float c2 = fmaxf(__builtin_amdgcn_fmed3f(a0, b1, b2),
                     __builtin_amdgcn_fmed3f(b0, a1, a2));
    a0 = c0; a1 = c1; a2 = c2;
}

// ---- fused prep: normalize queries (linear fp16) + supports (fp16, XOR-swizzled
// piece order within each 128B descriptor), coalesced 4KB block stores ----
__global__ __launch_bounds__(256) void prep(const float* __restrict__ x1,
                                            const float* __restrict__ x2,
                                            _Float16* __restrict__ qn,
                                            _Float16* __restrict__ sn) {
    __shared__ float ssred[256];
    __shared__ half8 obuf[256];     // 32 descriptors x 8 pieces = 4KB
    int tid = threadIdx.x;
    int ml = tid & 31, cg = tid >> 5;     // 32 descriptors x 8 c-groups
    float v[8];
    half8* dstblk;
    int wz;
    if (blockIdx.x < BB * 14) {           // queries: 16 b x 14 p-tiles of 32
        int b = blockIdx.x / 14, pt = blockIdx.x % 14;
        int p = pt * 32 + ml;
        const float* src = x1 + (size_t)b * CC * HW + p;
        bool real = p < HW;
        #pragma unroll
        for (int i = 0; i < 8; ++i) v[i] = real ? src[(size_t)(cg * 8 + i) * HW] : 0.f;
        wz = cg;                                            // linear
        dstblk = (half8*)(qn + ((size_t)(b * QP + pt * 32)) * CC);
    } else {                              // supports: 10 n x 69 m-tiles of 32
        int sb = blockIdx.x - BB * 14;
        int n = sb / 69, mt = sb % 69;
        int m = mt * 32 + ml;
        const float* src = x2 + (size_t)n * CC * MM + m;
        bool real = m < MM;
        #pragma unroll
        for (int i = 0; i < 8; ++i) v[i] = real ? src[(size_t)(cg * 8 + i) * MM] : 0.f;
        wz = cg ^ (ml & 7);                                 // bank-swizzled piece
        dstblk = (half8*)(sn + ((size_t)(n * MP + mt * 32)) * CC);
    }
    float ss = 0.f;
    #pragma unroll
    for (int i = 0; i < 8; ++i) ss += v[i] * v[i];
    ssred[tid] = ss;
    __syncthreads();
    float tot = 0.f;
    #pragma unroll
    for (int j = 0; j < 8; ++j) tot += ssred[j * 32 + ml];
    float inv = 1.f / fmaxf(sqrtf(tot), 1e-12f);
    half8 h;
    #pragma unroll
    for (int i = 0; i < 8; ++i) h[i] = (_Float16)(v[i] * inv);
    obuf[ml * 8 + wz] = h;
    __syncthreads();
    dstblk[tid] = obuf[tid];              // 256 x 16B contiguous
}

// ---- main: 4 waves x 7 q-tiles (A in regs, 14x reuse of every B-fragment),
// async LDS double-buffer staging, pair-max + top-2/slot ----
__global__ __launch_bounds__(256, 3) void img2class_mfma(const _Float16* __restrict__ qn,
                                                         const _Float16* __restrict__ sn,
                                                         float* __restrict__ partial) {
    __shared__ half8 ldsv[2 * CHUNK_T * 16 * 8];   // 2 x 12KB
    _Float16* lds = (_Float16*)ldsv;

    int ms = blockIdx.x & 7;          // m-split 0..7
    int bn = blockIdx.x >> 3;         // 0..159
    int b = bn / NCLS, n = bn % NCLS;
    int tid  = threadIdx.x;
    int wave = tid >> 6, lane = tid & 63;
    int col  = lane & 15, quad = lane >> 4;

    int p0  = ms * 9;                 // ms==7 -> 63
    int nch = (ms < 7) ? 3 : 2;       // 9 or 6 pairs

    // A fragments for 7 q-tiles (wave owns queries wave*112 .. +111)
    half8 A0[7], A1[7];
    const _Float16* abase = qn + ((size_t)(b * QP + wave * 112 + col)) * CC + quad * 8;
    #pragma unroll
    for (int qt = 0; qt < 7; ++qt) {
        A0[qt] = *(const half8*)(abase + qt * 16 * CC);
        A1[qt] = *(const half8*)(abase + qt * 16 * CC + 32);
    }

    float t0[7][4], t1[7][4];
    #pragma unroll
    for (int qt = 0; qt < 7; ++qt)
        #pragma unroll
        for (int r = 0; r < 4; ++r) { t0[qt][r] = -1.0e30f; t1[qt][r] = -1.0e30f; }

    // global tile 137 (pair 68 odd tile): real m only for col < 13
    float pen = (col >= 13) ? -1.0e30f : 0.0f;

    const char* sbase = (const char*)(sn + (size_t)n * MP * CC) + (size_t)p0 * 2 * 16 * CC * 2;
    int so = (wave * 3) * 1024 + lane * 16;
    char* lbase = (char*)lds;

    // prologue: chunk 0 -> buf 0
    #pragma unroll
    for (int i = 0; i < 3; ++i)
        GLDS16(sbase + so + i * 1024, lbase + (wave * 3 + i) * 1024);

    int swz0 = ((quad       ^ (col & 7)) << 3);
    int swz1 = (((4 + quad) ^ (col & 7)) << 3);

    for (int chunk = 0; chunk < nch; ++chunk) {
        if (chunk + 1 < nch) {
            const char* g = sbase + (size_t)(chunk + 1) * CHUNK_BYTES + so;
            char* l = lbase + ((chunk + 1) & 1) * CHUNK_BYTES + (wave * 3) * 1024;
            #pragma unroll
            for (int i = 0; i < 3; ++i)
                GLDS16(g + i * 1024, l + i * 1024);
            WAIT_VMCNT(3);     // current chunk resident; prefetch stays in flight
        } else {
            WAIT_VMCNT(0);
        }
        __builtin_amdgcn_s_barrier();

        const _Float16* lb = lds + (chunk & 1) * (CHUNK_T * 16 * CC);
        bool lastc = (ms == 7) && (chunk == nch - 1);
        #pragma unroll
        for (int pr = 0; pr < 3; ++pr) {
            int re = (pr * 2) * 16 + col;
            int ro = (pr * 2 + 1) * 16 + col;
            half8 B0e = *(const half8*)(lb + re * CC + swz0);
            half8 B1e = *(const half8*)(lb + re * CC + swz1);
            half8 B0o = *(const half8*)(lb + ro * CC + swz0);
            half8 B1o = *(const half8*)(lb + ro * CC + swz1);
            bool dopen = lastc && (pr == 2);
            #pragma unroll
            for (int qt = 0; qt < 7; ++qt) {
                float4_ z = {0.f, 0.f, 0.f, 0.f};
                float4_ ae = __builtin_amdgcn_mfma_f32_16x16x32_f16(A0[qt], B0e, z, 0, 0, 0);
                ae = __builtin_amdgcn_mfma_f32_16x16x32_f16(A1[qt], B1e, ae, 0, 0, 0);
                float4_ ao = __builtin_amdgcn_mfma_f32_16x16x32_f16(A0[qt], B0o, z, 0, 0, 0);
                ao = __builtin_amdgcn_mfma_f32_16x16x32_f16(A1[qt], B1o, ao, 0, 0, 0);
                if (dopen) { ao.x += pen; ao.y += pen; ao.z += pen; ao.w += pen; }
                ins2(fmaxf(ae.x, ao.x), t0[qt][0], t1[qt][0]);
                ins2(fmaxf(ae.y, ao.y), t0[qt][1], t1[qt][1]);
                ins2(fmaxf(ae.z, ao.z), t0[qt][2], t1[qt][2]);
                ins2(fmaxf(ae.w, ao.w), t0[qt][3], t1[qt][3]);
            }
        }
        __syncthreads();   // release buffer for next overwrite
    }

    // expand to triples (t2=-inf) and merge across the 16 m-columns
    #pragma unroll
    for (int qt = 0; qt < 7; ++qt) {
        #pragma unroll
        for (int r = 0; r < 4; ++r) {
            float a0 = t0[qt][r], a1 = t1[qt][r], a2 = -1.0e30f;
            #pragma unroll
            for (int s = 1; s <= 8; s <<= 1) {
                float b0 = __shfl_xor(a0, s);
                float b1 = __shfl_xor(a1, s);
                float b2 = __shfl_xor(a2, s);
                mrg3(b0, b1, b2, a0, a1, a2);
            }
            t0[qt][r] = a0; t1[qt][r] = a1;
            if (col == 0) {
                float* pp = partial + ((size_t)(bn * NSPLIT + ms) * QP
                                       + wave * 112 + qt * 16 + quad * 4 + r) * 3;
                pp[0] = a0; pp[1] = a1; pp[2] = a2;
            }
        }
    }
}

// ---- merge 8 m-splits per query, sum top-3, reduce over queries ----
__global__ __launch_bounds__(512) void merge_splits(const float* __restrict__ partial,
                                                    float* __restrict__ out) {
    __shared__ float red[512];
    int bn = blockIdx.x;
    int q  = threadIdx.x;
    float s = 0.f;
    if (q < HW) {
        const float* p = partial + ((size_t)(bn * NSPLIT) * QP + q) * 3;
        float a0 = p[0], a1 = p[1], a2 = p[2];
        #pragma unroll
        for (int sp = 1; sp < NSPLIT; ++sp) {
            const float* ps = p + (size_t)sp * QP * 3;
            mrg3(ps[0], ps[1], ps[2], a0, a1, a2);
        }
        s = a0 + a1 + a2;
    }
    red[q] = s;
    __syncthreads();
    #pragma unroll
    for (int stride = 256; stride >= 1; stride >>= 1) {
        if (q < stride) red[q] += red[q + stride];
        __syncthreads();
    }
    if (q == 0) out[bn] = red[0];
}

extern "C" void kernel_launch(void* const* d_in, const int* in_sizes, int n_in,
                              void* d_out, int out_size, void* d_ws, size_t ws_size,
                              hipStream_t stream) {
    const float* x1 = (const float*)d_in[0];   // [16,64,21,21]
    const float* x2 = (const float*)d_in[1];   // [10,64,2205]
    float* out = (float*)d_out;                // [16,10]

    _Float16* qn   = (_Float16*)d_ws;                  // 16*448*64 halves (linear)
    _Float16* sn   = qn + (size_t)BB * QP * CC;        // 10*2208*64 halves (swizzled)
    float* partial = (float*)(sn + (size_t)NCLS * MP * CC);  // 160*8*448*3 floats

    prep<<<BB * 14 + NCLS * 69, 256, 0, stream>>>(x1, x2, qn, sn);
    img2class_mfma<<<BB * NCLS * NSPLIT, 256, 0, stream>>>(qn, sn, partial);
    merge_splits<<<BB * NCLS, 512, 0, stream>>>(partial, out);
}

// Round 7
// 111.462 us; speedup vs baseline: 1.2661x; 1.2661x over previous
//
#include <hip/hip_runtime.h>
#include <math.h>

// Problem constants
#define BB    16      // batch
#define CC    64      // channels
#define HW    441     // h*w
#define QP    448     // padded to 28 tiles of 16
#define NCLS  10
#define MM    2205
#define MP    2208    // padded to 138 tiles of 16 = 69 pairs
#define NSPLIT 8      // m-splits: 7 splits of 9 pairs + 1 split of 6 pairs
#define CHUNK_T 6     // tiles per LDS chunk (3 pairs)
#define CHUNK_BYTES (CHUNK_T * 16 * CC * 2)   // 12288

typedef _Float16 half8 __attribute__((ext_vector_type(8)));
typedef float   float4_ __attribute__((ext_vector_type(4)));

// s_waitcnt with vmcnt(n), lgkmcnt/expcnt = no-wait (gfx9 encoding)
#define WAIT_VMCNT(n) __builtin_amdgcn_s_waitcnt(0x0F70 | (n))

// async global->LDS 16B per lane; lds dest = uniform base + lane*16
#define GLDS16(g, l) __builtin_amdgcn_global_load_lds(                         \
    (const __attribute__((address_space(1))) unsigned int*)(const void*)(g),   \
    (__attribute__((address_space(3))) unsigned int*)(void*)(l), 16, 0, 0)

// sorted top-2 insert (a0>=a1): 2 ops
__device__ __forceinline__ void ins2(float d, float& a0, float& a1) {
    float n0 = fmaxf(d, a0);
    float n1 = __builtin_amdgcn_fmed3f(d, a0, a1);
    a0 = n0; a1 = n1;
}

// merge sorted triple (b0>=b1>=b2) into sorted triple (a0>=a1>=a2): 6 ops
__device__ __forceinline__ void mrg3(float b0, float b1, float b2,
                                     float& a0, float& a1, float& a2) {
    float c0 = fmaxf(a0, b0);
    float c1 = fmaxf(fmaxf(fminf(a0, b0), a1), b1);
    float c2 = fmaxf(__builtin_amdgcn_fmed3f(a0, b1, b2),
                     __builtin_amdgcn_fmed3f(b0, a1, a2));
    a0 = c0; a1 = c1; a2 = c2;
}

// ---- fused prep: normalize queries (linear fp16) + supports (fp16, XOR-swizzled
// piece order within each 128B descriptor), coalesced 4KB block stores ----
__global__ __launch_bounds__(256) void prep(const float* __restrict__ x1,
                                            const float* __restrict__ x2,
                                            _Float16* __restrict__ qn,
                                            _Float16* __restrict__ sn) {
    __shared__ float ssred[256];
    __shared__ half8 obuf[256];     // 32 descriptors x 8 pieces = 4KB
    int tid = threadIdx.x;
    int ml = tid & 31, cg = tid >> 5;     // 32 descriptors x 8 c-groups
    float v[8];
    half8* dstblk;
    int wz;
    if (blockIdx.x < BB * 14) {           // queries: 16 b x 14 p-tiles of 32
        int b = blockIdx.x / 14, pt = blockIdx.x % 14;
        int p = pt * 32 + ml;
        const float* src = x1 + (size_t)b * CC * HW + p;
        bool real = p < HW;
        #pragma unroll
        for (int i = 0; i < 8; ++i) v[i] = real ? src[(size_t)(cg * 8 + i) * HW] : 0.f;
        wz = cg;                                            // linear
        dstblk = (half8*)(qn + ((size_t)(b * QP + pt * 32)) * CC);
    } else {                              // supports: 10 n x 69 m-tiles of 32
        int sb = blockIdx.x - BB * 14;
        int n = sb / 69, mt = sb % 69;
        int m = mt * 32 + ml;
        const float* src = x2 + (size_t)n * CC * MM + m;
        bool real = m < MM;
        #pragma unroll
        for (int i = 0; i < 8; ++i) v[i] = real ? src[(size_t)(cg * 8 + i) * MM] : 0.f;
        wz = cg ^ (ml & 7);                                 // bank-swizzled piece
        dstblk = (half8*)(sn + ((size_t)(n * MP + mt * 32)) * CC);
    }
    float ss = 0.f;
    #pragma unroll
    for (int i = 0; i < 8; ++i) ss += v[i] * v[i];
    ssred[tid] = ss;
    __syncthreads();
    float tot = 0.f;
    #pragma unroll
    for (int j = 0; j < 8; ++j) tot += ssred[j * 32 + ml];
    float inv = 1.f / fmaxf(sqrtf(tot), 1e-12f);
    half8 h;
    #pragma unroll
    for (int i = 0; i < 8; ++i) h[i] = (_Float16)(v[i] * inv);
    obuf[ml * 8 + wz] = h;
    __syncthreads();
    dstblk[tid] = obuf[tid];              // 256 x 16B contiguous
}

// ---- main: 4 waves x 7 q-tiles (A in regs, 14x reuse of every B-fragment),
// async LDS double-buffer staging, pair-max + top-2/slot.
// __launch_bounds__(256,2): VGPR cap 256 — demand ~180, NO SPILL (R6 lesson:
// (256,3) capped at ~170 and spilled 111 MB of scratch). ----
__global__ __launch_bounds__(256, 2) void img2class_mfma(const _Float16* __restrict__ qn,
                                                         const _Float16* __restrict__ sn,
                                                         float* __restrict__ partial) {
    __shared__ half8 ldsv[2 * CHUNK_T * 16 * 8];   // 2 x 12KB
    _Float16* lds = (_Float16*)ldsv;

    int ms = blockIdx.x & 7;          // m-split 0..7
    int bn = blockIdx.x >> 3;         // 0..159
    int b = bn / NCLS, n = bn % NCLS;
    int tid  = threadIdx.x;
    int wave = tid >> 6, lane = tid & 63;
    int col  = lane & 15, quad = lane >> 4;

    int p0  = ms * 9;                 // ms==7 -> 63
    int nch = (ms < 7) ? 3 : 2;       // 9 or 6 pairs

    // A fragments for 7 q-tiles (wave owns queries wave*112 .. +111)
    half8 A0[7], A1[7];
    const _Float16* abase = qn + ((size_t)(b * QP + wave * 112 + col)) * CC + quad * 8;
    #pragma unroll
    for (int qt = 0; qt < 7; ++qt) {
        A0[qt] = *(const half8*)(abase + qt * 16 * CC);
        A1[qt] = *(const half8*)(abase + qt * 16 * CC + 32);
    }

    float t0[7][4], t1[7][4];
    #pragma unroll
    for (int qt = 0; qt < 7; ++qt)
        #pragma unroll
        for (int r = 0; r < 4; ++r) { t0[qt][r] = -1.0e30f; t1[qt][r] = -1.0e30f; }

    // global tile 137 (pair 68 odd tile): real m only for col < 13
    float pen = (col >= 13) ? -1.0e30f : 0.0f;

    const char* sbase = (const char*)(sn + (size_t)n * MP * CC) + (size_t)p0 * 2 * 16 * CC * 2;
    int so = (wave * 3) * 1024 + lane * 16;
    char* lbase = (char*)lds;

    // prologue: chunk 0 -> buf 0
    #pragma unroll
    for (int i = 0; i < 3; ++i)
        GLDS16(sbase + so + i * 1024, lbase + (wave * 3 + i) * 1024);

    int swz0 = ((quad       ^ (col & 7)) << 3);
    int swz1 = (((4 + quad) ^ (col & 7)) << 3);

    for (int chunk = 0; chunk < nch; ++chunk) {
        if (chunk + 1 < nch) {
            const char* g = sbase + (size_t)(chunk + 1) * CHUNK_BYTES + so;
            char* l = lbase + ((chunk + 1) & 1) * CHUNK_BYTES + (wave * 3) * 1024;
            #pragma unroll
            for (int i = 0; i < 3; ++i)
                GLDS16(g + i * 1024, l + i * 1024);
            WAIT_VMCNT(3);     // current chunk resident; prefetch stays in flight
        } else {
            WAIT_VMCNT(0);
        }
        __builtin_amdgcn_s_barrier();

        const _Float16* lb = lds + (chunk & 1) * (CHUNK_T * 16 * CC);
        bool lastc = (ms == 7) && (chunk == nch - 1);
        #pragma unroll
        for (int pr = 0; pr < 3; ++pr) {
            int re = (pr * 2) * 16 + col;
            int ro = (pr * 2 + 1) * 16 + col;
            half8 B0e = *(const half8*)(lb + re * CC + swz0);
            half8 B1e = *(const half8*)(lb + re * CC + swz1);
            half8 B0o = *(const half8*)(lb + ro * CC + swz0);
            half8 B1o = *(const half8*)(lb + ro * CC + swz1);
            bool dopen = lastc && (pr == 2);
            #pragma unroll
            for (int qt = 0; qt < 7; ++qt) {
                float4_ z = {0.f, 0.f, 0.f, 0.f};
                float4_ ae = __builtin_amdgcn_mfma_f32_16x16x32_f16(A0[qt], B0e, z, 0, 0, 0);
                ae = __builtin_amdgcn_mfma_f32_16x16x32_f16(A1[qt], B1e, ae, 0, 0, 0);
                float4_ ao = __builtin_amdgcn_mfma_f32_16x16x32_f16(A0[qt], B0o, z, 0, 0, 0);
                ao = __builtin_amdgcn_mfma_f32_16x16x32_f16(A1[qt], B1o, ao, 0, 0, 0);
                if (dopen) { ao.x += pen; ao.y += pen; ao.z += pen; ao.w += pen; }
                ins2(fmaxf(ae.x, ao.x), t0[qt][0], t1[qt][0]);
                ins2(fmaxf(ae.y, ao.y), t0[qt][1], t1[qt][1]);
                ins2(fmaxf(ae.z, ao.z), t0[qt][2], t1[qt][2]);
                ins2(fmaxf(ae.w, ao.w), t0[qt][3], t1[qt][3]);
            }
        }
        __syncthreads();   // release buffer for next overwrite
    }

    // expand to triples (t2=-inf) and merge across the 16 m-columns
    #pragma unroll
    for (int qt = 0; qt < 7; ++qt) {
        #pragma unroll
        for (int r = 0; r < 4; ++r) {
            float a0 = t0[qt][r], a1 = t1[qt][r], a2 = -1.0e30f;
            #pragma unroll
            for (int s = 1; s <= 8; s <<= 1) {
                float b0 = __shfl_xor(a0, s);
                float b1 = __shfl_xor(a1, s);
                float b2 = __shfl_xor(a2, s);
                mrg3(b0, b1, b2, a0, a1, a2);
            }
            if (col == 0) {
                float* pp = partial + ((size_t)(bn * NSPLIT + ms) * QP
                                       + wave * 112 + qt * 16 + quad * 4 + r) * 3;
                pp[0] = a0; pp[1] = a1; pp[2] = a2;
            }
        }
    }
}

// ---- merge 8 m-splits per query, sum top-3, reduce over queries ----
__global__ __launch_bounds__(512) void merge_splits(const float* __restrict__ partial,
                                                    float* __restrict__ out) {
    __shared__ float red[512];
    int bn = blockIdx.x;
    int q  = threadIdx.x;
    float s = 0.f;
    if (q < HW) {
        const float* p = partial + ((size_t)(bn * NSPLIT) * QP + q) * 3;
        float a0 = p[0], a1 = p[1], a2 = p[2];
        #pragma unroll
        for (int sp = 1; sp < NSPLIT; ++sp) {
            const float* ps = p + (size_t)sp * QP * 3;
            mrg3(ps[0], ps[1], ps[2], a0, a1, a2);
        }
        s = a0 + a1 + a2;
    }
    red[q] = s;
    __syncthreads();
    #pragma unroll
    for (int stride = 256; stride >= 1; stride >>= 1) {
        if (q < stride) red[q] += red[q + stride];
        __syncthreads();
    }
    if (q == 0) out[bn] = red[0];
}

extern "C" void kernel_launch(void* const* d_in, const int* in_sizes, int n_in,
                              void* d_out, int out_size, void* d_ws, size_t ws_size,
                              hipStream_t stream) {
    const float* x1 = (const float*)d_in[0];   // [16,64,21,21]
    const float* x2 = (const float*)d_in[1];   // [10,64,2205]
    float* out = (float*)d_out;                // [16,10]

    _Float16* qn   = (_Float16*)d_ws;                  // 16*448*64 halves (linear)
    _Float16* sn   = qn + (size_t)BB * QP * CC;        // 10*2208*64 halves (swizzled)
    float* partial = (float*)(sn + (size_t)NCLS * MP * CC);  // 160*8*448*3 floats

    prep<<<BB * 14 + NCLS * 69, 256, 0, stream>>>(x1, x2, qn, sn);
    img2class_mfma<<<BB * NCLS * NSPLIT, 256, 0, stream>>>(qn, sn, partial);
    merge_splits<<<BB * NCLS, 512, 0, stream>>>(partial, out);
}

// Round 8
// 106.625 us; speedup vs baseline: 1.3236x; 1.0454x over previous
//
#include <hip/hip_runtime.h>
#include <math.h>

// Problem constants
#define BB    16      // batch
#define CC    64      // channels
#define HW    441     // h*w
#define QP    448     // padded to 28 tiles of 16
#define NCLS  10
#define MM    2205
#define MP    2208    // padded to 138 tiles of 16 = 69 pairs
#define NSPLIT 8      // m-splits: 7 splits of 9 pairs + 1 split of 6 pairs
#define CHUNK_T 6     // tiles per LDS chunk (3 pairs)
#define CHUNK_BYTES (CHUNK_T * 16 * CC * 2)   // 12288

typedef _Float16 half8 __attribute__((ext_vector_type(8)));
typedef float   float4_ __attribute__((ext_vector_type(4)));
typedef float   float2_ __attribute__((ext_vector_type(2)));

// s_waitcnt with vmcnt(n), lgkmcnt/expcnt = no-wait (gfx9 encoding)
#define WAIT_VMCNT(n) __builtin_amdgcn_s_waitcnt(0x0F70 | (n))

// async global->LDS 16B per lane; lds dest = uniform base + lane*16
#define GLDS16(g, l) __builtin_amdgcn_global_load_lds(                         \
    (const __attribute__((address_space(1))) unsigned int*)(const void*)(g),   \
    (__attribute__((address_space(3))) unsigned int*)(void*)(l), 16, 0, 0)

// sorted top-2 insert (a0>=a1): 2 ops
__device__ __forceinline__ void ins2(float d, float& a0, float& a1) {
    float n0 = fmaxf(d, a0);
    float n1 = __builtin_amdgcn_fmed3f(d, a0, a1);
    a0 = n0; a1 = n1;
}

// merge two sorted pairs keeping exact top-2: 3 ops
// c0 = max(a0,b0); c1 = second-largest = med3(a0, b0, max(a1,b1))
__device__ __forceinline__ void mrgp(float b0, float b1, float& a0, float& a1) {
    float c1 = __builtin_amdgcn_fmed3f(a0, b0, fmaxf(a1, b1));
    a0 = fmaxf(a0, b0);
    a1 = c1;
}

// insert sorted pair (d0>=d1) into sorted triple (a0>=a1>=a2): 5 ops
__device__ __forceinline__ void inspair3(float d0, float d1,
                                         float& a0, float& a1, float& a2) {
    float n0 = fmaxf(a0, d0);
    float n1 = __builtin_amdgcn_fmed3f(d0, a0, a1);
    float n2 = __builtin_amdgcn_fmed3f(d0, a1, a2);
    float m1 = fmaxf(n1, d1);
    float m2 = __builtin_amdgcn_fmed3f(d1, n1, n2);
    a0 = n0; a1 = m1; a2 = m2;
}

// ---- fused prep: normalize queries (linear fp16) + supports (fp16, XOR-swizzled
// piece order within each 128B descriptor), coalesced 4KB block stores ----
__global__ __launch_bounds__(256) void prep(const float* __restrict__ x1,
                                            const float* __restrict__ x2,
                                            _Float16* __restrict__ qn,
                                            _Float16* __restrict__ sn) {
    __shared__ float ssred[256];
    __shared__ half8 obuf[256];     // 32 descriptors x 8 pieces = 4KB
    int tid = threadIdx.x;
    int ml = tid & 31, cg = tid >> 5;     // 32 descriptors x 8 c-groups
    float v[8];
    half8* dstblk;
    int wz;
    if (blockIdx.x < BB * 14) {           // queries: 16 b x 14 p-tiles of 32
        int b = blockIdx.x / 14, pt = blockIdx.x % 14;
        int p = pt * 32 + ml;
        const float* src = x1 + (size_t)b * CC * HW + p;
        bool real = p < HW;
        #pragma unroll
        for (int i = 0; i < 8; ++i) v[i] = real ? src[(size_t)(cg * 8 + i) * HW] : 0.f;
        wz = cg;                                            // linear
        dstblk = (half8*)(qn + ((size_t)(b * QP + pt * 32)) * CC);
    } else {                              // supports: 10 n x 69 m-tiles of 32
        int sb = blockIdx.x - BB * 14;
        int n = sb / 69, mt = sb % 69;
        int m = mt * 32 + ml;
        const float* src = x2 + (size_t)n * CC * MM + m;
        bool real = m < MM;
        #pragma unroll
        for (int i = 0; i < 8; ++i) v[i] = real ? src[(size_t)(cg * 8 + i) * MM] : 0.f;
        wz = cg ^ (ml & 7);                                 // bank-swizzled piece
        dstblk = (half8*)(sn + ((size_t)(n * MP + mt * 32)) * CC);
    }
    float ss = 0.f;
    #pragma unroll
    for (int i = 0; i < 8; ++i) ss += v[i] * v[i];
    ssred[tid] = ss;
    __syncthreads();
    float tot = 0.f;
    #pragma unroll
    for (int j = 0; j < 8; ++j) tot += ssred[j * 32 + ml];
    float inv = 1.f / fmaxf(sqrtf(tot), 1e-12f);
    half8 h;
    #pragma unroll
    for (int i = 0; i < 8; ++i) h[i] = (_Float16)(v[i] * inv);
    obuf[ml * 8 + wz] = h;
    __syncthreads();
    dstblk[tid] = obuf[tid];              // 256 x 16B contiguous
}

// ---- main: 4 waves x 7 q-tiles (A in regs, 14x B reuse), async LDS double-buffer,
// pair-max + top-2/slot; SHALLOW epilogue: 3-step pair-butterfly (exact top-2 per
// 8-col group), lanes col in {0,8} store float2 -> merge kernel finishes top-3.
// (R7 lesson: depth-4 triple butterfly = serialized ds_bpermute chains, waves 85% stalled) ----
__global__ __launch_bounds__(256, 2) void img2class_mfma(const _Float16* __restrict__ qn,
                                                         const _Float16* __restrict__ sn,
                                                         float2_* __restrict__ partial) {
    __shared__ half8 ldsv[2 * CHUNK_T * 16 * 8];   // 2 x 12KB
    _Float16* lds = (_Float16*)ldsv;

    int ms = blockIdx.x & 7;          // m-split 0..7
    int bn = blockIdx.x >> 3;         // 0..159
    int b = bn / NCLS, n = bn % NCLS;
    int tid  = threadIdx.x;
    int wave = tid >> 6, lane = tid & 63;
    int col  = lane & 15, quad = lane >> 4;

    int p0  = ms * 9;                 // ms==7 -> 63
    int nch = (ms < 7) ? 3 : 2;       // 9 or 6 pairs

    // A fragments for 7 q-tiles (wave owns queries wave*112 .. +111)
    half8 A0[7], A1[7];
    const _Float16* abase = qn + ((size_t)(b * QP + wave * 112 + col)) * CC + quad * 8;
    #pragma unroll
    for (int qt = 0; qt < 7; ++qt) {
        A0[qt] = *(const half8*)(abase + qt * 16 * CC);
        A1[qt] = *(const half8*)(abase + qt * 16 * CC + 32);
    }

    float t0[7][4], t1[7][4];
    #pragma unroll
    for (int qt = 0; qt < 7; ++qt)
        #pragma unroll
        for (int r = 0; r < 4; ++r) { t0[qt][r] = -1.0e30f; t1[qt][r] = -1.0e30f; }

    // global tile 137 (pair 68 odd tile): real m only for col < 13
    float pen = (col >= 13) ? -1.0e30f : 0.0f;

    const char* sbase = (const char*)(sn + (size_t)n * MP * CC) + (size_t)p0 * 2 * 16 * CC * 2;
    int so = (wave * 3) * 1024 + lane * 16;
    char* lbase = (char*)lds;

    // prologue: chunk 0 -> buf 0
    #pragma unroll
    for (int i = 0; i < 3; ++i)
        GLDS16(sbase + so + i * 1024, lbase + (wave * 3 + i) * 1024);

    int swz0 = ((quad       ^ (col & 7)) << 3);
    int swz1 = (((4 + quad) ^ (col & 7)) << 3);

    for (int chunk = 0; chunk < nch; ++chunk) {
        if (chunk + 1 < nch) {
            const char* g = sbase + (size_t)(chunk + 1) * CHUNK_BYTES + so;
            char* l = lbase + ((chunk + 1) & 1) * CHUNK_BYTES + (wave * 3) * 1024;
            #pragma unroll
            for (int i = 0; i < 3; ++i)
                GLDS16(g + i * 1024, l + i * 1024);
            WAIT_VMCNT(3);     // current chunk resident; prefetch stays in flight
        } else {
            WAIT_VMCNT(0);
        }
        __builtin_amdgcn_s_barrier();

        const _Float16* lb = lds + (chunk & 1) * (CHUNK_T * 16 * CC);
        bool lastc = (ms == 7) && (chunk == nch - 1);
        #pragma unroll
        for (int pr = 0; pr < 3; ++pr) {
            int re = (pr * 2) * 16 + col;
            int ro = (pr * 2 + 1) * 16 + col;
            half8 B0e = *(const half8*)(lb + re * CC + swz0);
            half8 B1e = *(const half8*)(lb + re * CC + swz1);
            half8 B0o = *(const half8*)(lb + ro * CC + swz0);
            half8 B1o = *(const half8*)(lb + ro * CC + swz1);
            bool dopen = lastc && (pr == 2);
            #pragma unroll
            for (int qt = 0; qt < 7; ++qt) {
                float4_ z = {0.f, 0.f, 0.f, 0.f};
                float4_ ae = __builtin_amdgcn_mfma_f32_16x16x32_f16(A0[qt], B0e, z, 0, 0, 0);
                ae = __builtin_amdgcn_mfma_f32_16x16x32_f16(A1[qt], B1e, ae, 0, 0, 0);
                float4_ ao = __builtin_amdgcn_mfma_f32_16x16x32_f16(A0[qt], B0o, z, 0, 0, 0);
                ao = __builtin_amdgcn_mfma_f32_16x16x32_f16(A1[qt], B1o, ao, 0, 0, 0);
                if (dopen) { ao.x += pen; ao.y += pen; ao.z += pen; ao.w += pen; }
                ins2(fmaxf(ae.x, ao.x), t0[qt][0], t1[qt][0]);
                ins2(fmaxf(ae.y, ao.y), t0[qt][1], t1[qt][1]);
                ins2(fmaxf(ae.z, ao.z), t0[qt][2], t1[qt][2]);
                ins2(fmaxf(ae.w, ao.w), t0[qt][3], t1[qt][3]);
            }
        }
        __syncthreads();   // release buffer for next overwrite
    }

    // shallow pair-butterfly: 3 steps (xor 1,2,4) keeping exact top-2 of the
    // growing col-group; lanes col 0 and 8 write their 8-col-group top-2.
    size_t pbase = (size_t)(bn * NSPLIT + ms) * QP;
    int g = col >> 3;                  // 0 or 1
    bool writer = (col & 7) == 0;
    #pragma unroll
    for (int qt = 0; qt < 7; ++qt) {
        #pragma unroll
        for (int r = 0; r < 4; ++r) {
            float a0 = t0[qt][r], a1 = t1[qt][r];
            #pragma unroll
            for (int s = 1; s <= 4; s <<= 1) {
                float b0 = __shfl_xor(a0, s);
                float b1 = __shfl_xor(a1, s);
                mrgp(b0, b1, a0, a1);
            }
            if (writer) {
                int q = wave * 112 + qt * 16 + quad * 4 + r;
                float2_ v2; v2.x = a0; v2.y = a1;
                partial[(pbase + q) * 2 + g] = v2;
            }
        }
    }
}

// ---- merge: per (bn), each thread owns one query: top-3 of 16 sorted pairs
// (8 splits x 2 col-groups), sum, LDS-reduce over queries ----
__global__ __launch_bounds__(448) void merge_splits(const float2_* __restrict__ partial,
                                                    float* __restrict__ out) {
    __shared__ float red[512];
    int bn = blockIdx.x;
    int q  = threadIdx.x;      // 0..447
    float a0 = -1.0e30f, a1 = -1.0e30f, a2 = -1.0e30f;
    #pragma unroll
    for (int sp = 0; sp < NSPLIT; ++sp) {
        const float2_* p = partial + ((size_t)(bn * NSPLIT + sp) * QP + q) * 2;
        float2_ v0 = p[0];
        float2_ v1 = p[1];
        inspair3(v0.x, v0.y, a0, a1, a2);
        inspair3(v1.x, v1.y, a0, a1, a2);
    }
    float s = (q < HW) ? (a0 + a1 + a2) : 0.f;
    red[q] = s;
    if (q < 64) red[448 + q] = 0.f;
    __syncthreads();
    #pragma unroll
    for (int stride = 256; stride >= 1; stride >>= 1) {
        if (q < stride && q + stride < 512) red[q] += red[q + stride];
        __syncthreads();
    }
    if (q == 0) out[bn] = red[0];
}

extern "C" void kernel_launch(void* const* d_in, const int* in_sizes, int n_in,
                              void* d_out, int out_size, void* d_ws, size_t ws_size,
                              hipStream_t stream) {
    const float* x1 = (const float*)d_in[0];   // [16,64,21,21]
    const float* x2 = (const float*)d_in[1];   // [10,64,2205]
    float* out = (float*)d_out;                // [16,10]

    _Float16* qn    = (_Float16*)d_ws;                 // 16*448*64 halves (linear)
    _Float16* sn    = qn + (size_t)BB * QP * CC;       // 10*2208*64 halves (swizzled)
    float2_* partial = (float2_*)(sn + (size_t)NCLS * MP * CC);  // 160*8*448*2 float2

    prep<<<BB * 14 + NCLS * 69, 256, 0, stream>>>(x1, x2, qn, sn);
    img2class_mfma<<<BB * NCLS * NSPLIT, 256, 0, stream>>>(qn, sn, partial);
    merge_splits<<<BB * NCLS, 448, 0, stream>>>(partial, out);
}